// Round 11
// baseline (185.591 us; speedup 1.0000x reference)
//
#include <hip/hip_runtime.h>
#include <hip/hip_bf16.h>

#define Bb 16
#define Tt 512
#define Hh 1024
#define NHd 16
#define HD 64
#define BT (Bb*Tt)
#define NSK 50
#define NIT 1000

typedef __attribute__((ext_vector_type(8))) short bf16x8;
typedef __attribute__((ext_vector_type(4))) float f32x4;
typedef unsigned short u16;
typedef unsigned int u32;
typedef unsigned long long u64;

__device__ inline u16 f2bf(float x){
  union { float f; u32 u; } v; v.f = x;
  u32 r = v.u + 0x7fffu + ((v.u >> 16) & 1u);
  return (u16)(r >> 16);
}
__device__ inline float bf2f(u32 u){
  union { u32 uu; float f; } v; v.uu = u << 16; return v.f;
}
__device__ inline u32 pack2bf(float lo, float hi){
  return (u32)f2bf(lo) | ((u32)f2bf(hi) << 16);
}
__device__ inline void gload_lds16(const void* g, void* l){
  __builtin_amdgcn_global_load_lds(
    (const __attribute__((address_space(1))) u32*)g,
    (__attribute__((address_space(3))) u32*)l, 16, 0, 0);
}

// ---------------- prep: weight transposes + pmask + wpt + uv partials + build_x ----------------
// z=0..3: wq/wk/wv/wo transposes; z=4: w_hid (gamma-folded) + uvp
// z=5: pmask; z=6: w_prob^T; z=7: x = emb[prob_x] + PE -> bf16
__global__ __launch_bounds__(256) void k_wT_all(
    const float* __restrict__ wq, const float* __restrict__ wk,
    const float* __restrict__ wv, const float* __restrict__ wo,
    const float* __restrict__ wh, const float* __restrict__ gamma,
    const float* __restrict__ beta,
    const int* __restrict__ prob_x, const float* __restrict__ qm,
    const float* __restrict__ wp, const float* __restrict__ emb,
    u16* __restrict__ wqkvT, u16* __restrict__ woT, u16* __restrict__ whT,
    float2* __restrict__ uvp, u64* __restrict__ pmask, float* __restrict__ wpt,
    u16* __restrict__ xb){
  int z = blockIdx.z;
  int tid = threadIdx.x;
  if (z == 5){
    if (blockIdx.y) return;
    int i = blockIdx.x*256 + tid;
    int pid = (prob_x[i] - 4) >> 1;
    u64 m = 0ull;
    #pragma unroll
    for (int s = 0; s < NSK; s++)
      if (qm[s*NIT + pid] != 0.f) m |= (1ull << s);
    pmask[i] = m;
    return;
  }
  if (z == 6){
    int blk = blockIdx.y*32 + blockIdx.x;
    if (blk >= 250) return;
    int p = blk*4 + (tid >> 6), lane = tid & 63;
    if (lane < NSK) wpt[(size_t)p*64 + lane] = wp[(size_t)lane*NIT + p];
    return;
  }
  if (z == 7){
    int blk = blockIdx.y*32 + blockIdx.x;    // 0..1023, 8 rows each
    int h = tid*4, j0 = h >> 1;
    const float LOG_INC = 0.0180241495f;     // ln(10000)/511
    float e0 = __expf(-(float)j0 * LOG_INC);
    float e1 = __expf(-(float)(j0+1) * LOG_INC);
    #pragma unroll
    for (int rr = 0; rr < 8; rr++){
      int bt = blk*8 + rr;
      int t = bt & (Tt-1);
      int ix = prob_x[bt];
      float4 e = *(const float4*)(emb + (size_t)ix*Hh + h);
      float a0 = (float)t * e0, a1 = (float)t * e1;
      alignas(8) u16 tmp[4] = { f2bf(e.x + __sinf(a0)), f2bf(e.y + __cosf(a0)),
                                f2bf(e.z + __sinf(a1)), f2bf(e.w + __cosf(a1)) };
      *(uint2*)(xb + (size_t)bt*Hh + h) = *(const uint2*)tmp;
    }
    return;
  }
  const float* src; u16* dst; int C = 1024; float scale = 1.f; bool useg = false;
  if      (z == 0){ src = wq; dst = wqkvT;                       scale = 0.125f; }
  else if (z == 1){ src = wk; dst = wqkvT + (size_t)1024*1024; }
  else if (z == 2){ src = wv; dst = wqkvT + (size_t)2*1024*1024; }
  else if (z == 3){ src = wo; dst = woT; }
  else            { src = wh; dst = whT; C = 100; useg = true; if (blockIdx.x >= 4) return; }

  __shared__ float tile[32][33];
  int tx = tid & 31, ty = tid >> 5;
  int c0 = blockIdx.x*32, r0 = blockIdx.y*32;
  #pragma unroll
  for (int i = 0; i < 32; i += 8){
    int r = r0 + ty + i, cc = c0 + tx;
    tile[ty+i][tx] = (cc < C) ? src[(size_t)r*C + cc] : 0.f;
  }
  __syncthreads();
  float gmul = useg ? gamma[r0 + tx] : scale;
  #pragma unroll
  for (int i = 0; i < 32; i += 8){
    int cc = c0 + ty + i, rr = r0 + tx;
    dst[(size_t)cc*1024 + rr] = f2bf(tile[tx][ty+i] * gmul);
  }
  if (useg && tid < 32){
    int j = tid;
    float us = 0.f, vs = 0.f;
    #pragma unroll
    for (int k = 0; k < 32; k++){
      float wv2 = tile[k][j];
      us += gamma[r0 + k] * wv2;
      vs += beta[r0 + k] * wv2;
    }
    uvp[(size_t)blockIdx.y*128 + c0 + j] = make_float2(us, vs);
  }
}

// =========== 128(M) x 256(N) GEMM core: triple-buffered, 1 barrier/K-tile ===========
#define MFMA_(d, va, vb) d = __builtin_amdgcn_mfma_f32_16x16x32_bf16(va, vb, d, 0, 0, 0)

__device__ __forceinline__ void gemm128x256_core(
    const u16* __restrict__ A, const u16* __restrict__ Bt,
    int row0, int col0, char* lds, f32x4 (&acc)[4][4])
{
  const int tid = threadIdx.x, w = tid >> 6, lane = tid & 63;
  const int c = lane & 15, g = lane >> 4;
  const int wm = w >> 2, wn = w & 3;
  const int srl = lane >> 3, scb = lane & 7;
  const int kbsw = scb ^ srl;

  #define STAGE6(buf, k0)                                                        \
    do {                                                                         \
      char* _da = lds + (buf)*49152 + w*2048;                                    \
      char* _db = lds + (buf)*49152 + 16384 + w*4096;                            \
      _Pragma("unroll")                                                          \
      for (int i = 0; i < 2; i++)                                                \
        gload_lds16(A + (size_t)(row0 + 16*w + 8*i + srl)*1024 + (k0) + kbsw*8,  \
                    _da + i*1024);                                               \
      _Pragma("unroll")                                                          \
      for (int i = 0; i < 4; i++)                                                \
        gload_lds16(Bt + (size_t)(col0 + 32*w + 8*i + srl)*1024 + (k0) + kbsw*8, \
                    _db + i*1024);                                               \
    } while (0)

  STAGE6(0, 0);
  STAGE6(1, 64);
  asm volatile("s_waitcnt vmcnt(6)" ::: "memory");
  __builtin_amdgcn_s_barrier();

  #pragma unroll
  for (int kt = 0; kt < 16; ++kt){
    const int buf = kt % 3;
    if (kt + 2 < 16) STAGE6((kt + 2) % 3, (kt + 2)*64);

    bf16x8 af[2][4], bf[2][4];
    #pragma unroll
    for (int kh = 0; kh < 2; kh++){
      #pragma unroll
      for (int mi = 0; mi < 4; mi++){
        int r = 64*wm + 16*mi + c;
        af[kh][mi] = *(const bf16x8*)(lds + buf*49152 + r*128 + (((kh*4 + g) ^ (c & 7))*16));
      }
      #pragma unroll
      for (int ni = 0; ni < 4; ni++){
        int r = 64*wn + 16*ni + c;
        bf[kh][ni] = *(const bf16x8*)(lds + buf*49152 + 16384 + r*128 + (((kh*4 + g) ^ (c & 7))*16));
      }
    }
    __builtin_amdgcn_s_setprio(1);
    #pragma unroll
    for (int kh = 0; kh < 2; kh++)
      #pragma unroll
      for (int mi = 0; mi < 4; mi++)
        #pragma unroll
        for (int ni = 0; ni < 4; ni++) MFMA_(acc[mi][ni], af[kh][mi], bf[kh][ni]);
    __builtin_amdgcn_s_setprio(0);

    if (kt < 15){
      if (kt < 14) asm volatile("s_waitcnt vmcnt(6)" ::: "memory");
      else         asm volatile("s_waitcnt vmcnt(0)" ::: "memory");
      __builtin_amdgcn_s_barrier();
    }
  }
  #undef STAGE6
}

// =========== fused QKV GEMM: 768 blocks; XCD owns 8 row-panels, bx inner ===========
__global__ __launch_bounds__(512) void k_gemm_qkv3(
    const u16* __restrict__ A, const u16* __restrict__ Bt,
    u16* __restrict__ qb, u16* __restrict__ kb, u16* __restrict__ vtb)
{
  extern __shared__ char lds[];
  int lin = blockIdx.x;
  int xcd = lin & 7, j = lin >> 3;
  int by = xcd*8 + (j & 7);
  int bx = j >> 3;
  const int row0 = by*128, col0 = bx*256;

  f32x4 acc[4][4];
  #pragma unroll
  for (int mi = 0; mi < 4; mi++)
    #pragma unroll
    for (int ni = 0; ni < 4; ni++) acc[mi][ni] = (f32x4){0.f,0.f,0.f,0.f};

  gemm128x256_core(A, Bt, row0, col0, lds, acc);

  const int tid = threadIdx.x, w = tid >> 6, lane = tid & 63;
  const int c = lane & 15, g = lane >> 4;
  const int wm = w >> 2, wn = w & 3;
  int seg = col0 >> 10;
  int colL0 = col0 & 1023;
  if (seg < 2){
    u16* C = seg ? kb : qb;
    #pragma unroll
    for (int mi = 0; mi < 4; mi++){
      int m0 = row0 + 64*wm + 16*mi + 4*g;
      int bb = m0 >> 9, t0 = m0 & (Tt-1);
      #pragma unroll
      for (int ni = 0; ni < 4; ni++){
        int col = colL0 + 64*wn + 16*ni + c;
        int hd_ = col >> 6, d_ = col & 63;
        u16* base = C + (((size_t)bb*NHd + hd_)*Tt + t0)*HD + d_;
        #pragma unroll
        for (int r = 0; r < 4; r++) base[(size_t)r*HD] = f2bf(acc[mi][ni][r]);
      }
    }
  } else {
    #pragma unroll
    for (int mi = 0; mi < 4; mi++){
      int m0 = row0 + 64*wm + 16*mi + 4*g;
      int bb = m0 >> 9, t0 = m0 & (Tt-1);
      #pragma unroll
      for (int ni = 0; ni < 4; ni++){
        int col = colL0 + 64*wn + 16*ni + c;
        int hd_ = col >> 6, d_ = col & 63;
        alignas(8) u16 tmp[4];
        #pragma unroll
        for (int r = 0; r < 4; r++) tmp[r] = f2bf(acc[mi][ni][r]);
        *(uint2*)(vtb + (((size_t)bb*NHd + hd_)*HD + d_)*Tt + t0) = *(const uint2*)tmp;
      }
    }
  }
}

// =========== WO GEMM: 256 blocks; residual + LN stats ===========
__global__ __launch_bounds__(512) void k_gemm_wo3(
    const u16* __restrict__ A, const u16* __restrict__ Bt,
    u16* __restrict__ C, const u16* __restrict__ res, float2* __restrict__ stats)
{
  extern __shared__ char lds[];
  int lin = blockIdx.x;
  int xcd = lin & 7, j = lin >> 3;
  int by = xcd*8 + (j & 7);
  int bx = j >> 3;
  const int row0 = by*128, col0 = bx*256;

  f32x4 acc[4][4];
  #pragma unroll
  for (int mi = 0; mi < 4; mi++)
    #pragma unroll
    for (int ni = 0; ni < 4; ni++) acc[mi][ni] = (f32x4){0.f,0.f,0.f,0.f};

  gemm128x256_core(A, Bt, row0, col0, lds, acc);

  const int tid = threadIdx.x, w = tid >> 6, lane = tid & 63;
  const int c = lane & 15, g = lane >> 4;
  const int wm = w >> 2, wn = w & 3;

  float s1[4][4], s2[4][4];
  #pragma unroll
  for (int mi = 0; mi < 4; mi++)
    #pragma unroll
    for (int r = 0; r < 4; r++){ s1[mi][r] = 0.f; s2[mi][r] = 0.f; }

  #pragma unroll
  for (int mi = 0; mi < 4; mi++){
    int m0 = row0 + 64*wm + 16*mi + 4*g;
    #pragma unroll
    for (int ni = 0; ni < 4; ni++){
      int col = col0 + 64*wn + 16*ni + c;
      #pragma unroll
      for (int r = 0; r < 4; r++){
        size_t idx = (size_t)(m0 + r)*Hh + col;
        float yv = acc[mi][ni][r] + bf2f((u32)res[idx]);
        C[idx] = f2bf(yv);
        s1[mi][r] += yv; s2[mi][r] += yv*yv;
      }
    }
  }
  #pragma unroll
  for (int mi = 0; mi < 4; mi++)
    #pragma unroll
    for (int r = 0; r < 4; r++){
      #pragma unroll
      for (int off = 1; off < 16; off <<= 1){
        s1[mi][r] += __shfl_xor(s1[mi][r], off);
        s2[mi][r] += __shfl_xor(s2[mi][r], off);
      }
    }
  __syncthreads();
  float (*sStat)[4][2] = (float(*)[4][2])lds;
  if (c == 0){
    #pragma unroll
    for (int mi = 0; mi < 4; mi++)
      #pragma unroll
      for (int r = 0; r < 4; r++){
        int ml = 64*wm + 16*mi + 4*g + r;
        sStat[ml][wn][0] = s1[mi][r];
        sStat[ml][wn][1] = s2[mi][r];
      }
  }
  __syncthreads();
  if (tid < 128){
    float a = sStat[tid][0][0] + sStat[tid][1][0] + sStat[tid][2][0] + sStat[tid][3][0];
    float b = sStat[tid][0][1] + sStat[tid][1][1] + sStat[tid][2][1] + sStat[tid][3][1];
    stats[(size_t)(row0 + tid)*4 + bx] = make_float2(a, b);
  }
}

// =========== hidden GEMM + fused LN + fused tail: BM=32, 256 blocks ===========
__global__ __launch_bounds__(256) void k_gemm_hidden(
    const u16* __restrict__ A, const u16* __restrict__ Bt,
    const float2* __restrict__ stats, const float2* __restrict__ uvp,
    const float* __restrict__ b_hid, const int* __restrict__ prob_y2,
    const float* __restrict__ w_skill, const float* __restrict__ b_skill,
    const float* __restrict__ wpt, const float* __restrict__ b_prob,
    float* __restrict__ out)
{
  __shared__ u16 sA[32*64];
  __shared__ u16 sB[128*64];
  __shared__ float sMu[32][2];
  __shared__ float2 sUV[128];
  const int tid = threadIdx.x, w = tid >> 6, lane = tid & 63;
  const int c = lane & 15, g = lane >> 4;
  const int row0 = blockIdx.x*32;
  const int srl = lane >> 3, scb = lane & 7;

  if (tid < 32){
    float m = 0.f, q = 0.f;
    #pragma unroll
    for (int cb = 0; cb < 4; cb++){
      float2 s = stats[(size_t)(row0 + tid)*4 + cb];
      m += s.x; q += s.y;
    }
    float mu = m * (1.f/Hh);
    float var = q * (1.f/Hh) - mu*mu;
    sMu[tid][0] = mu;
    sMu[tid][1] = rsqrtf(var + 1e-3f);
  }
  if (tid < 128){
    float us = 0.f, vs = 0.f;
    #pragma unroll 8
    for (int cb = 0; cb < 32; cb++){
      float2 p = uvp[(size_t)cb*128 + tid];
      us += p.x; vs += p.y;
    }
    float2 r = make_float2(0.f, 0.f);
    if (tid < 100){ r.x = us; r.y = vs + b_hid[tid]; }
    sUV[tid] = r;
  }

  f32x4 acc[2][2];
  #pragma unroll
  for (int mi = 0; mi < 2; mi++)
    #pragma unroll
    for (int ni = 0; ni < 2; ni++) acc[mi][ni] = (f32x4){0.f,0.f,0.f,0.f};

  for (int k0 = 0; k0 < 1024; k0 += 64){
    __syncthreads();
    {
      int arow = 8*w + srl;
      int kblk = scb ^ (arow & 7);
      gload_lds16(A + (size_t)(row0 + arow)*1024 + k0 + kblk*8,
                  (char*)sA + w*1024);
      #pragma unroll
      for (int i = 0; i < 4; i++){
        int brow = 32*w + 8*i + srl;
        int kb2 = scb ^ (brow & 7);
        gload_lds16(Bt + (size_t)brow*1024 + k0 + kb2*8,
                    (char*)sB + w*4096 + i*1024);
      }
    }
    __syncthreads();

    #pragma unroll
    for (int kh = 0; kh < 2; kh++){
      bf16x8 af[2], bf[2];
      #pragma unroll
      for (int mi = 0; mi < 2; mi++){
        int r = 16*mi + c;
        af[mi] = *(const bf16x8*)((char*)sA + r*128 + (((4*kh + g) ^ (r & 7))*16));
      }
      #pragma unroll
      for (int ni = 0; ni < 2; ni++){
        int r = 32*w + 16*ni + c;
        bf[ni] = *(const bf16x8*)((char*)sB + r*128 + (((4*kh + g) ^ (r & 7))*16));
      }
      #pragma unroll
      for (int mi = 0; mi < 2; mi++)
        #pragma unroll
        for (int ni = 0; ni < 2; ni++)
          acc[mi][ni] = __builtin_amdgcn_mfma_f32_16x16x32_bf16(af[mi], bf[ni], acc[mi][ni], 0, 0, 0);
    }
  }

  // h -> LDS (reuse sB as float[32][128])
  __syncthreads();
  float* sHf = (float*)sB;
  #pragma unroll
  for (int mi = 0; mi < 2; mi++){
    #pragma unroll
    for (int ni = 0; ni < 2; ni++){
      int col = 32*w + 16*ni + c;
      float2 uvv = sUV[col];
      #pragma unroll
      for (int r = 0; r < 4; r++){
        int ml = 16*mi + 4*g + r;
        float mu = sMu[ml][0], inv = sMu[ml][1];
        sHf[ml*128 + col] = fmaxf(inv*(acc[mi][ni][r] - mu*uvv.x) + uvv.y, 0.f);
      }
    }
  }
  __syncthreads();

  // fused tail: 8 threads per row; j strided by 8 over 50 outputs
  {
    int row = tid >> 3, sub = tid & 7;
    int bt = row0 + row;
    int np = (prob_y2[bt] - 4) >> 1;
    const float* hrow = sHf + row*128;
    float z = 0.f;
    for (int jj = sub; jj < NSK; jj += 8){
      float s = b_skill[jj];
      #pragma unroll 4
      for (int i = 0; i < 100; i++) s += hrow[i] * w_skill[i*NSK + jj];
      z += s * wpt[(size_t)np*64 + jj];
    }
    z += __shfl_xor(z, 1);
    z += __shfl_xor(z, 2);
    z += __shfl_xor(z, 4);
    if (sub == 0) out[bt] = 1.f/(1.f + __expf(-(z + b_prob[np])));
  }
}

// =========== MFMA flash attention, swapped-operand structure ===========
__global__ __launch_bounds__(256, 3) void k_flash(
    const u16* __restrict__ qb, const u16* __restrict__ kb,
    const u16* __restrict__ vtb, const u64* __restrict__ pmask,
    u16* __restrict__ o)
{
  __shared__ u16 sK[2][64*64];
  __shared__ u16 sV[2][64*64];
  __shared__ u16 sP[4][32*64];

  const int tid = threadIdx.x;
  const int w = tid >> 6, lane = tid & 63;
  const int c = lane & 15, g = lane >> 4;
  const int bn = blockIdx.x;
  const int Fblk = 3 - blockIdx.y;
  const int b = bn >> 4, n = bn & 15;
  const int f0w = Fblk*128 + w*32;

  bf16x8 qf[2][2];
  #pragma unroll
  for (int fb = 0; fb < 2; fb++){
    const u16* qrow = qb + ((size_t)bn*Tt + f0w + 16*fb + c)*HD + 8*g;
    qf[fb][0] = *(const bf16x8*)(qrow);
    qf[fb][1] = *(const bf16x8*)(qrow + 32);
  }

  const u64* pmb = pmask + b*Tt;
  int frow[2]; u64 mf[2];
  #pragma unroll
  for (int fb = 0; fb < 2; fb++){ frow[fb] = f0w + 16*fb + c; mf[fb] = pmb[frow[fb]]; }

  f32x4 O[2][4];
  #pragma unroll
  for (int fb = 0; fb < 2; fb++)
    #pragma unroll
    for (int dt = 0; dt < 4; dt++) O[fb][dt] = (f32x4){0.f,0.f,0.f,0.f};
  float m_run[2] = {-1e30f, -1e30f};
  float l_run[2] = {0.f, 0.f};

  const char* kbase = (const char*)(kb + (size_t)bn*Tt*HD);
  const char* vbase = (const char*)(vtb + (size_t)bn*HD*Tt);
  char* sPw = (char*)(sP[w]);

  const int srow0 = 16*w + (lane >> 3);
  const int scb = lane & 7;

  #define STAGE(buf, T0)                                                          \
    {                                                                             \
      _Pragma("unroll")                                                           \
      for (int i = 0; i < 2; i++){                                                \
        int row = srow0 + 8*i;                                                    \
        int cb = scb ^ (row & 7);                                                 \
        gload_lds16(kbase + (size_t)((T0) + row)*128 + cb*16,                     \
                    (char*)sK[buf] + w*2048 + i*1024);                            \
        gload_lds16(vbase + (size_t)row*1024 + (T0)*2 + cb*16,                    \
                    (char*)sV[buf] + w*2048 + i*1024);                            \
      }                                                                           \
    }

  const int nT = 2*Fblk + 2;
  STAGE(0, 0)
  __syncthreads();
  int cur = 0;

  for (int it = 0; it < nT; ++it){
    const int t0 = it * 64;
    if (it + 1 < nT) STAGE(cur^1, (it+1)*64)

    if (t0 <= f0w + 31){
      const char* sKc = (const char*)sK[cur];
      const char* sVc = (const char*)sV[cur];
      const bool fullcausal = (t0 >= 64) && (t0 + 63 <= f0w);

      f32x4 S[2][4];
      __builtin_amdgcn_s_setprio(1);
      #pragma unroll
      for (int ts = 0; ts < 4; ts++){
        int tl = ts*16 + c;
        const char* kr = sKc + tl*128;
        int sw = (tl & 7) << 4;
        bf16x8 kf0 = *(const bf16x8*)(kr + ((g*16) ^ sw));
        bf16x8 kf1 = *(const bf16x8*)(kr + ((64 + g*16) ^ sw));
        #pragma unroll
        for (int fb = 0; fb < 2; fb++){
          f32x4 a = (f32x4){0.f,0.f,0.f,0.f};
          a = __builtin_amdgcn_mfma_f32_16x16x32_bf16(kf0, qf[fb][0], a, 0, 0, 0);
          a = __builtin_amdgcn_mfma_f32_16x16x32_bf16(kf1, qf[fb][1], a, 0, 0, 0);
          S[fb][ts] = a;
        }
      }
      __builtin_amdgcn_s_setprio(0);

      u64 pmt[4][4];
      #pragma unroll
      for (int ts = 0; ts < 4; ts++){
        const u64* pp = pmb + t0 + 16*ts + 4*g;
        pmt[ts][0] = pp[0]; pmt[ts][1] = pp[1];
        pmt[ts][2] = pp[2]; pmt[ts][3] = pp[3];
      }

      #pragma unroll
      for (int fb = 0; fb < 2; fb++){
        int f = frow[fb];
        u64 mfr = mf[fb];
        if (fullcausal){
          #pragma unroll
          for (int ts = 0; ts < 4; ts++)
            #pragma unroll
            for (int r = 0; r < 4; r++)
              if (!(pmt[ts][r] & mfr)) S[fb][ts][r] = -1e30f;
        } else {
          #pragma unroll
          for (int ts = 0; ts < 4; ts++){
            #pragma unroll
            for (int r = 0; r < 4; r++){
              int t = t0 + 16*ts + 4*g + r;
              bool ok = (f == 0) ? (t == 0)
                       : (t > 0 && t <= f && ((pmt[ts][r] & mfr) != 0ull));
              if (!ok) S[fb][ts][r] = -1e30f;
            }
          }
        }
        float mx = -1e30f;
        #pragma unroll
        for (int ts = 0; ts < 4; ts++)
          #pragma unroll
          for (int r = 0; r < 4; r++) mx = fmaxf(mx, S[fb][ts][r]);
        mx = fmaxf(mx, __shfl_xor(mx, 16));
        mx = fmaxf(mx, __shfl_xor(mx, 32));

        float mnew;
        if (__all(mx <= m_run[fb] + 8.f)){
          mnew = m_run[fb];                 // defer-max: skip rescale (T13)
        } else {
          mnew = fmaxf(m_run[fb], mx);
          float al = __expf(m_run[fb] - mnew);
          m_run[fb] = mnew;
          l_run[fb] *= al;
          #pragma unroll
          for (int dt = 0; dt < 4; dt++) O[fb][dt] *= al;
        }

        int prow = 16*fb + c;
        int swz = (prow & 7) << 4;
        float lsum = 0.f;
        #pragma unroll
        for (int ts = 0; ts < 4; ts++){
          float p0 = __expf(S[fb][ts][0] - mnew);
          float p1 = __expf(S[fb][ts][1] - mnew);
          float p2 = __expf(S[fb][ts][2] - mnew);
          float p3 = __expf(S[fb][ts][3] - mnew);
          lsum += (p0 + p1) + (p2 + p3);
          uint2 dw = { pack2bf(p0, p1), pack2bf(p2, p3) };
          *(uint2*)(sPw + prow*128 + ((32*ts + 8*g) ^ swz)) = dw;
        }
        l_run[fb] += lsum;
      }

      bf16x8 pa[2][2];
      #pragma unroll
      for (int fb = 0; fb < 2; fb++){
        int prow = 16*fb + c;
        int swz = (prow & 7) << 4;
        const char* pr = sPw + prow*128;
        pa[fb][0] = *(const bf16x8*)(pr + ((16*g) ^ swz));
        pa[fb][1] = *(const bf16x8*)(pr + ((64 + 16*g) ^ swz));
      }
      __builtin_amdgcn_s_setprio(1);
      #pragma unroll
      for (int dt = 0; dt < 4; dt++){
        int vl = dt*16 + c;
        const char* vr = sVc + vl*128;
        int swv = (vl & 7) << 4;
        bf16x8 vf0 = *(const bf16x8*)(vr + ((g*16) ^ swv));
        bf16x8 vf1 = *(const bf16x8*)(vr + ((64 + g*16) ^ swv));
        #pragma unroll
        for (int fb = 0; fb < 2; fb++){
          O[fb][dt] = __builtin_amdgcn_mfma_f32_16x16x32_bf16(vf0, pa[fb][0], O[fb][dt], 0, 0, 0);
          O[fb][dt] = __builtin_amdgcn_mfma_f32_16x16x32_bf16(vf1, pa[fb][1], O[fb][dt], 0, 0, 0);
        }
      }
      __builtin_amdgcn_s_setprio(0);
    }

    __syncthreads();
    cur ^= 1;
  }
  #undef STAGE

  #pragma unroll
  for (int fb = 0; fb < 2; fb++){
    float l = l_run[fb];
    l += __shfl_xor(l, 16);
    l += __shfl_xor(l, 32);
    float inv = 1.f / l;
    u16* ob = o + ((size_t)(b*Tt + frow[fb]))*Hh + n*HD;
    #pragma unroll
    for (int dt = 0; dt < 4; dt++){
      alignas(8) u16 tmp[4];
      #pragma unroll
      for (int r = 0; r < 4; r++) tmp[r] = f2bf(O[fb][dt][r] * inv);
      *(uint2*)(ob + dt*16 + 4*g) = *(const uint2*)tmp;
    }
  }
}

extern "C" void kernel_launch(void* const* d_in, const int* in_sizes, int n_in,
                              void* d_out, int out_size, void* d_ws, size_t ws_size,
                              hipStream_t stream)
{
  const int*   prob_x   = (const int*)d_in[0];
  const int*   prob_y2  = (const int*)d_in[1];
  const float* emb      = (const float*)d_in[2];
  const float* wq       = (const float*)d_in[3];
  const float* wk       = (const float*)d_in[4];
  const float* wv       = (const float*)d_in[5];
  const float* wo       = (const float*)d_in[6];
  const float* ln_g     = (const float*)d_in[7];
  const float* ln_b     = (const float*)d_in[8];
  const float* w_hid    = (const float*)d_in[9];
  const float* b_hid    = (const float*)d_in[10];
  const float* w_skill  = (const float*)d_in[11];
  const float* b_skill  = (const float*)d_in[12];
  const float* w_prob   = (const float*)d_in[13];
  const float* b_prob   = (const float*)d_in[14];
  const float* q_matrix = (const float*)d_in[15];
  float* out = (float*)d_out;

  char* ws = (char*)d_ws;
  const size_t M16 = (size_t)BT*Hh*2;   // 16 MiB
  u16*   xb     = (u16*)(ws);
  u16*   qb     = (u16*)(ws + M16);
  u16*   kb     = (u16*)(ws + 2*M16);
  u16*   vtb    = (u16*)(ws + 3*M16);
  u16*   att    = (u16*)(ws + 4*M16);
  u16*   y      = qb;      // dead after flash
  char*  aux    = ws + 5*M16;
  u16*   wqkvT  = (u16*)(aux);                            // 6 MiB
  u16*   woT    = wqkvT + (size_t)3*1024*1024;            // 2 MiB
  u16*   whT    = woT + (size_t)1024*1024;                // 256 KiB
  float* wpt    = (float*)(whT + (size_t)128*1024);       // 256 KiB
  u64*   pmask  = (u64*)(wpt + (size_t)NIT*64);           // 64 KiB
  float2* stats = (float2*)((char*)pmask + (size_t)BT*8); // 256 KiB used
  float2* uvp   = (float2*)((char*)stats + (size_t)BT*8*sizeof(float2)); // 32 KiB

  k_wT_all<<<dim3(32,32,8), 256, 0, stream>>>(wq, wk, wv, wo, w_hid, ln_g, ln_b,
                                              prob_x, q_matrix, w_prob, emb,
                                              wqkvT, woT, whT, uvp, pmask, wpt, xb);

  k_gemm_qkv3<<<768, 512, 147456, stream>>>(xb, wqkvT, qb, kb, vtb);

  k_flash<<<dim3(Bb*NHd, 4), 256, 0, stream>>>(qb, kb, vtb, pmask, att);

  k_gemm_wo3<<<256, 512, 147456, stream>>>(att, woT, y, xb, stats);

  k_gemm_hidden<<<256, 256, 0, stream>>>(y, whT, stats, uvp, b_hid,
                                         prob_y2, w_skill, b_skill, wpt, b_prob, out);
}

// Round 12
// 176.447 us; speedup vs baseline: 1.0518x; 1.0518x over previous
//
#include <hip/hip_runtime.h>
#include <hip/hip_bf16.h>

#define Bb 16
#define Tt 512
#define Hh 1024
#define NHd 16
#define HD 64
#define BT (Bb*Tt)
#define NSK 50
#define NIT 1000

typedef __attribute__((ext_vector_type(8))) short bf16x8;
typedef __attribute__((ext_vector_type(4))) float f32x4;
typedef unsigned short u16;
typedef unsigned int u32;
typedef unsigned long long u64;

__device__ inline u16 f2bf(float x){
  union { float f; u32 u; } v; v.f = x;
  u32 r = v.u + 0x7fffu + ((v.u >> 16) & 1u);
  return (u16)(r >> 16);
}
__device__ inline float bf2f(u32 u){
  union { u32 uu; float f; } v; v.uu = u << 16; return v.f;
}
__device__ inline u32 pack2bf(float lo, float hi){
  return (u32)f2bf(lo) | ((u32)f2bf(hi) << 16);
}
__device__ inline void gload_lds16(const void* g, void* l){
  __builtin_amdgcn_global_load_lds(
    (const __attribute__((address_space(1))) u32*)g,
    (__attribute__((address_space(3))) u32*)l, 16, 0, 0);
}

// ---------------- weight transposes + pmask + wpt + uv partials, one launch ----------------
__global__ __launch_bounds__(256) void k_wT_all(
    const float* __restrict__ wq, const float* __restrict__ wk,
    const float* __restrict__ wv, const float* __restrict__ wo,
    const float* __restrict__ wh, const float* __restrict__ gamma,
    const float* __restrict__ beta,
    const int* __restrict__ prob_x, const float* __restrict__ qm,
    const float* __restrict__ wp,
    u16* __restrict__ wqkvT, u16* __restrict__ woT, u16* __restrict__ whT,
    float2* __restrict__ uvp, u64* __restrict__ pmask, float* __restrict__ wpt){
  int z = blockIdx.z;
  int tid = threadIdx.x;
  if (z == 5){
    if (blockIdx.y) return;
    int i = blockIdx.x*256 + tid;
    int pid = (prob_x[i] - 4) >> 1;
    u64 m = 0ull;
    #pragma unroll
    for (int s = 0; s < NSK; s++)
      if (qm[s*NIT + pid] != 0.f) m |= (1ull << s);
    pmask[i] = m;
    return;
  }
  if (z == 6){
    int blk = blockIdx.y*32 + blockIdx.x;
    if (blk >= 250) return;
    int p = blk*4 + (tid >> 6), lane = tid & 63;
    if (lane < NSK) wpt[(size_t)p*64 + lane] = wp[(size_t)lane*NIT + p];
    return;
  }
  const float* src; u16* dst; int C = 1024; float scale = 1.f; bool useg = false;
  if      (z == 0){ src = wq; dst = wqkvT;                       scale = 0.125f; }
  else if (z == 1){ src = wk; dst = wqkvT + (size_t)1024*1024; }
  else if (z == 2){ src = wv; dst = wqkvT + (size_t)2*1024*1024; }
  else if (z == 3){ src = wo; dst = woT; }
  else            { src = wh; dst = whT; C = 100; useg = true; if (blockIdx.x >= 4) return; }

  __shared__ float tile[32][33];
  int tx = tid & 31, ty = tid >> 5;
  int c0 = blockIdx.x*32, r0 = blockIdx.y*32;
  #pragma unroll
  for (int i = 0; i < 32; i += 8){
    int r = r0 + ty + i, cc = c0 + tx;
    tile[ty+i][tx] = (cc < C) ? src[(size_t)r*C + cc] : 0.f;
  }
  __syncthreads();
  float gmul = useg ? gamma[r0 + tx] : scale;
  #pragma unroll
  for (int i = 0; i < 32; i += 8){
    int cc = c0 + ty + i, rr = r0 + tx;
    dst[(size_t)cc*1024 + rr] = f2bf(tile[tx][ty+i] * gmul);
  }
  if (useg && tid < 32){
    int j = tid;
    float us = 0.f, vs = 0.f;
    #pragma unroll
    for (int k = 0; k < 32; k++){
      float wv2 = tile[k][j];
      us += gamma[r0 + k] * wv2;
      vs += beta[r0 + k] * wv2;
    }
    uvp[(size_t)blockIdx.y*128 + c0 + j] = make_float2(us, vs);
  }
}

// ---------------- x = emb[prob_x] + pe (inline) : bf16 ----------------
__global__ __launch_bounds__(256) void k_build_x2(
    const int* __restrict__ prob_x, const float* __restrict__ emb,
    u16* __restrict__ xb){
  int bt = blockIdx.x, tid = threadIdx.x;
  int t = bt & (Tt-1);
  int ix = prob_x[bt];
  int h = tid*4;
  float4 e = *(const float4*)(emb + (size_t)ix*Hh + h);
  const float LOG_INC = 0.0180241495f;   // ln(10000)/511
  int j0 = h >> 1;
  float a0 = (float)t * __expf(-(float)j0 * LOG_INC);
  float a1 = (float)t * __expf(-(float)(j0+1) * LOG_INC);
  alignas(8) u16 tmp[4] = { f2bf(e.x + __sinf(a0)), f2bf(e.y + __cosf(a0)),
                            f2bf(e.z + __sinf(a1)), f2bf(e.w + __cosf(a1)) };
  *(uint2*)(xb + (size_t)bt*Hh + h) = *(const uint2*)tmp;
}

// =========== 128(M) x 256(N) GEMM core: triple-buffered, 1 barrier/K-tile ===========
#define MFMA_(d, va, vb) d = __builtin_amdgcn_mfma_f32_16x16x32_bf16(va, vb, d, 0, 0, 0)

__device__ __forceinline__ void gemm128x256_core(
    const u16* __restrict__ A, const u16* __restrict__ Bt,
    int row0, int col0, char* lds, f32x4 (&acc)[4][4])
{
  const int tid = threadIdx.x, w = tid >> 6, lane = tid & 63;
  const int c = lane & 15, g = lane >> 4;
  const int wm = w >> 2, wn = w & 3;
  const int srl = lane >> 3, scb = lane & 7;
  const int kbsw = scb ^ srl;

  #define STAGE6(buf, k0)                                                        \
    do {                                                                         \
      char* _da = lds + (buf)*49152 + w*2048;                                    \
      char* _db = lds + (buf)*49152 + 16384 + w*4096;                            \
      _Pragma("unroll")                                                          \
      for (int i = 0; i < 2; i++)                                                \
        gload_lds16(A + (size_t)(row0 + 16*w + 8*i + srl)*1024 + (k0) + kbsw*8,  \
                    _da + i*1024);                                               \
      _Pragma("unroll")                                                          \
      for (int i = 0; i < 4; i++)                                                \
        gload_lds16(Bt + (size_t)(col0 + 32*w + 8*i + srl)*1024 + (k0) + kbsw*8, \
                    _db + i*1024);                                               \
    } while (0)

  STAGE6(0, 0);
  STAGE6(1, 64);
  asm volatile("s_waitcnt vmcnt(6)" ::: "memory");
  __builtin_amdgcn_s_barrier();

  #pragma unroll
  for (int kt = 0; kt < 16; ++kt){
    const int buf = kt % 3;
    if (kt + 2 < 16) STAGE6((kt + 2) % 3, (kt + 2)*64);

    bf16x8 af[2][4], bf[2][4];
    #pragma unroll
    for (int kh = 0; kh < 2; kh++){
      #pragma unroll
      for (int mi = 0; mi < 4; mi++){
        int r = 64*wm + 16*mi + c;
        af[kh][mi] = *(const bf16x8*)(lds + buf*49152 + r*128 + (((kh*4 + g) ^ (c & 7))*16));
      }
      #pragma unroll
      for (int ni = 0; ni < 4; ni++){
        int r = 64*wn + 16*ni + c;
        bf[kh][ni] = *(const bf16x8*)(lds + buf*49152 + 16384 + r*128 + (((kh*4 + g) ^ (c & 7))*16));
      }
    }
    __builtin_amdgcn_s_setprio(1);
    #pragma unroll
    for (int kh = 0; kh < 2; kh++)
      #pragma unroll
      for (int mi = 0; mi < 4; mi++)
        #pragma unroll
        for (int ni = 0; ni < 4; ni++) MFMA_(acc[mi][ni], af[kh][mi], bf[kh][ni]);
    __builtin_amdgcn_s_setprio(0);

    if (kt < 15){
      if (kt < 14) asm volatile("s_waitcnt vmcnt(6)" ::: "memory");
      else         asm volatile("s_waitcnt vmcnt(0)" ::: "memory");
      __builtin_amdgcn_s_barrier();
    }
  }
  #undef STAGE6
}

// =========== fused QKV GEMM: 768 blocks; XCD owns 8 row-panels, bx inner ===========
__global__ __launch_bounds__(512) void k_gemm_qkv3(
    const u16* __restrict__ A, const u16* __restrict__ Bt,
    u16* __restrict__ qb, u16* __restrict__ kb, u16* __restrict__ vtb)
{
  extern __shared__ char lds[];
  int lin = blockIdx.x;
  int xcd = lin & 7, j = lin >> 3;
  int by = xcd*8 + (j & 7);
  int bx = j >> 3;
  const int row0 = by*128, col0 = bx*256;

  f32x4 acc[4][4];
  #pragma unroll
  for (int mi = 0; mi < 4; mi++)
    #pragma unroll
    for (int ni = 0; ni < 4; ni++) acc[mi][ni] = (f32x4){0.f,0.f,0.f,0.f};

  gemm128x256_core(A, Bt, row0, col0, lds, acc);

  const int tid = threadIdx.x, w = tid >> 6, lane = tid & 63;
  const int c = lane & 15, g = lane >> 4;
  const int wm = w >> 2, wn = w & 3;
  int seg = col0 >> 10;
  int colL0 = col0 & 1023;
  if (seg < 2){
    u16* C = seg ? kb : qb;
    #pragma unroll
    for (int mi = 0; mi < 4; mi++){
      int m0 = row0 + 64*wm + 16*mi + 4*g;
      int bb = m0 >> 9, t0 = m0 & (Tt-1);
      #pragma unroll
      for (int ni = 0; ni < 4; ni++){
        int col = colL0 + 64*wn + 16*ni + c;
        int hd_ = col >> 6, d_ = col & 63;
        u16* base = C + (((size_t)bb*NHd + hd_)*Tt + t0)*HD + d_;
        #pragma unroll
        for (int r = 0; r < 4; r++) base[(size_t)r*HD] = f2bf(acc[mi][ni][r]);
      }
    }
  } else {
    #pragma unroll
    for (int mi = 0; mi < 4; mi++){
      int m0 = row0 + 64*wm + 16*mi + 4*g;
      int bb = m0 >> 9, t0 = m0 & (Tt-1);
      #pragma unroll
      for (int ni = 0; ni < 4; ni++){
        int col = colL0 + 64*wn + 16*ni + c;
        int hd_ = col >> 6, d_ = col & 63;
        alignas(8) u16 tmp[4];
        #pragma unroll
        for (int r = 0; r < 4; r++) tmp[r] = f2bf(acc[mi][ni][r]);
        *(uint2*)(vtb + (((size_t)bb*NHd + hd_)*HD + d_)*Tt + t0) = *(const uint2*)tmp;
      }
    }
  }
}

// =========== WO GEMM: 256 blocks; residual + LN stats ===========
__global__ __launch_bounds__(512) void k_gemm_wo3(
    const u16* __restrict__ A, const u16* __restrict__ Bt,
    u16* __restrict__ C, const u16* __restrict__ res, float2* __restrict__ stats)
{
  extern __shared__ char lds[];
  int lin = blockIdx.x;
  int xcd = lin & 7, j = lin >> 3;
  int by = xcd*8 + (j & 7);
  int bx = j >> 3;
  const int row0 = by*128, col0 = bx*256;

  f32x4 acc[4][4];
  #pragma unroll
  for (int mi = 0; mi < 4; mi++)
    #pragma unroll
    for (int ni = 0; ni < 4; ni++) acc[mi][ni] = (f32x4){0.f,0.f,0.f,0.f};

  gemm128x256_core(A, Bt, row0, col0, lds, acc);

  const int tid = threadIdx.x, w = tid >> 6, lane = tid & 63;
  const int c = lane & 15, g = lane >> 4;
  const int wm = w >> 2, wn = w & 3;

  float s1[4][4], s2[4][4];
  #pragma unroll
  for (int mi = 0; mi < 4; mi++)
    #pragma unroll
    for (int r = 0; r < 4; r++){ s1[mi][r] = 0.f; s2[mi][r] = 0.f; }

  #pragma unroll
  for (int mi = 0; mi < 4; mi++){
    int m0 = row0 + 64*wm + 16*mi + 4*g;
    #pragma unroll
    for (int ni = 0; ni < 4; ni++){
      int col = col0 + 64*wn + 16*ni + c;
      #pragma unroll
      for (int r = 0; r < 4; r++){
        size_t idx = (size_t)(m0 + r)*Hh + col;
        float yv = acc[mi][ni][r] + bf2f((u32)res[idx]);
        C[idx] = f2bf(yv);
        s1[mi][r] += yv; s2[mi][r] += yv*yv;
      }
    }
  }
  #pragma unroll
  for (int mi = 0; mi < 4; mi++)
    #pragma unroll
    for (int r = 0; r < 4; r++){
      #pragma unroll
      for (int off = 1; off < 16; off <<= 1){
        s1[mi][r] += __shfl_xor(s1[mi][r], off);
        s2[mi][r] += __shfl_xor(s2[mi][r], off);
      }
    }
  __syncthreads();
  float (*sStat)[4][2] = (float(*)[4][2])lds;
  if (c == 0){
    #pragma unroll
    for (int mi = 0; mi < 4; mi++)
      #pragma unroll
      for (int r = 0; r < 4; r++){
        int ml = 64*wm + 16*mi + 4*g + r;
        sStat[ml][wn][0] = s1[mi][r];
        sStat[ml][wn][1] = s2[mi][r];
      }
  }
  __syncthreads();
  if (tid < 128){
    float a = sStat[tid][0][0] + sStat[tid][1][0] + sStat[tid][2][0] + sStat[tid][3][0];
    float b = sStat[tid][0][1] + sStat[tid][1][1] + sStat[tid][2][1] + sStat[tid][3][1];
    stats[(size_t)(row0 + tid)*4 + bx] = make_float2(a, b);
  }
}

// =========== hidden GEMM with fused LayerNorm: BM=32, BN=128, 256 blocks ===========
__global__ __launch_bounds__(256) void k_gemm_hidden(
    const u16* __restrict__ A, const u16* __restrict__ Bt,
    const float2* __restrict__ stats, const float2* __restrict__ uvp,
    const float* __restrict__ b_hid, u16* __restrict__ C)
{
  __shared__ u16 sA[32*64];
  __shared__ u16 sB[128*64];
  __shared__ float sMu[32][2];
  __shared__ float2 sUV[128];
  const int tid = threadIdx.x, w = tid >> 6, lane = tid & 63;
  const int c = lane & 15, g = lane >> 4;
  const int row0 = blockIdx.x*32;
  const int srl = lane >> 3, scb = lane & 7;

  if (tid < 32){
    float m = 0.f, q = 0.f;
    #pragma unroll
    for (int cb = 0; cb < 4; cb++){
      float2 s = stats[(size_t)(row0 + tid)*4 + cb];
      m += s.x; q += s.y;
    }
    float mu = m * (1.f/Hh);
    float var = q * (1.f/Hh) - mu*mu;
    sMu[tid][0] = mu;
    sMu[tid][1] = rsqrtf(var + 1e-3f);
  }
  if (tid < 128){
    float us = 0.f, vs = 0.f;
    #pragma unroll 8
    for (int cb = 0; cb < 32; cb++){
      float2 p = uvp[(size_t)cb*128 + tid];
      us += p.x; vs += p.y;
    }
    float2 r = make_float2(0.f, 0.f);
    if (tid < 100){ r.x = us; r.y = vs + b_hid[tid]; }
    sUV[tid] = r;
  }

  f32x4 acc[2][2];
  #pragma unroll
  for (int mi = 0; mi < 2; mi++)
    #pragma unroll
    for (int ni = 0; ni < 2; ni++) acc[mi][ni] = (f32x4){0.f,0.f,0.f,0.f};

  for (int k0 = 0; k0 < 1024; k0 += 64){
    __syncthreads();
    {
      int arow = 8*w + srl;
      int kblk = scb ^ (arow & 7);
      gload_lds16(A + (size_t)(row0 + arow)*1024 + k0 + kblk*8,
                  (char*)sA + w*1024);
      #pragma unroll
      for (int i = 0; i < 4; i++){
        int brow = 32*w + 8*i + srl;
        int kb2 = scb ^ (brow & 7);
        gload_lds16(Bt + (size_t)brow*1024 + k0 + kb2*8,
                    (char*)sB + w*4096 + i*1024);
      }
    }
    __syncthreads();

    #pragma unroll
    for (int kh = 0; kh < 2; kh++){
      bf16x8 af[2], bf[2];
      #pragma unroll
      for (int mi = 0; mi < 2; mi++){
        int r = 16*mi + c;
        af[mi] = *(const bf16x8*)((char*)sA + r*128 + (((4*kh + g) ^ (r & 7))*16));
      }
      #pragma unroll
      for (int ni = 0; ni < 2; ni++){
        int r = 32*w + 16*ni + c;
        bf[ni] = *(const bf16x8*)((char*)sB + r*128 + (((4*kh + g) ^ (r & 7))*16));
      }
      #pragma unroll
      for (int mi = 0; mi < 2; mi++)
        #pragma unroll
        for (int ni = 0; ni < 2; ni++)
          acc[mi][ni] = __builtin_amdgcn_mfma_f32_16x16x32_bf16(af[mi], bf[ni], acc[mi][ni], 0, 0, 0);
    }
  }

  #pragma unroll
  for (int mi = 0; mi < 2; mi++){
    #pragma unroll
    for (int ni = 0; ni < 2; ni++){
      int col = 32*w + 16*ni + c;
      float2 uvv = sUV[col];
      #pragma unroll
      for (int r = 0; r < 4; r++){
        int ml = 16*mi + 4*g + r;
        float mu = sMu[ml][0], inv = sMu[ml][1];
        float h = fmaxf(inv*(acc[mi][ni][r] - mu*uvv.x) + uvv.y, 0.f);
        C[(size_t)(row0 + ml)*128 + col] = f2bf(h);
      }
    }
  }
}

// =========== MFMA flash attention, swapped-operand; paired F-blocks (balanced) ===========
// blockIdx.y in [0,2): pass 0 -> Fblk = 3-y, pass 1 -> Fblk = y.
// Pairs (3,0) and (2,1): every block stages exactly 10 tiles -> 512 equal blocks.
__global__ __launch_bounds__(256, 3) void k_flash(
    const u16* __restrict__ qb, const u16* __restrict__ kb,
    const u16* __restrict__ vtb, const u64* __restrict__ pmask,
    u16* __restrict__ o)
{
  __shared__ u16 sK[2][64*64];
  __shared__ u16 sV[2][64*64];
  __shared__ u16 sP[4][32*64];

  const int tid = threadIdx.x;
  const int w = tid >> 6, lane = tid & 63;
  const int c = lane & 15, g = lane >> 4;
  const int bn = blockIdx.x;
  const int b = bn >> 4, n = bn & 15;

  const u64* pmb = pmask + b*Tt;
  const char* kbase = (const char*)(kb + (size_t)bn*Tt*HD);
  const char* vbase = (const char*)(vtb + (size_t)bn*HD*Tt);
  char* sPw = (char*)(sP[w]);

  const int srow0 = 16*w + (lane >> 3);
  const int scb = lane & 7;

  #define STAGE(buf, T0)                                                          \
    {                                                                             \
      _Pragma("unroll")                                                           \
      for (int i = 0; i < 2; i++){                                                \
        int row = srow0 + 8*i;                                                    \
        int cb = scb ^ (row & 7);                                                 \
        gload_lds16(kbase + (size_t)((T0) + row)*128 + cb*16,                     \
                    (char*)sK[buf] + w*2048 + i*1024);                            \
        gload_lds16(vbase + (size_t)row*1024 + (T0)*2 + cb*16,                    \
                    (char*)sV[buf] + w*2048 + i*1024);                            \
      }                                                                           \
    }

  for (int pass = 0; pass < 2; ++pass){
    const int Fblk = pass ? (int)blockIdx.y : 3 - (int)blockIdx.y;
    const int f0w = Fblk*128 + w*32;

    bf16x8 qf[2][2];
    #pragma unroll
    for (int fb = 0; fb < 2; fb++){
      const u16* qrow = qb + ((size_t)bn*Tt + f0w + 16*fb + c)*HD + 8*g;
      qf[fb][0] = *(const bf16x8*)(qrow);
      qf[fb][1] = *(const bf16x8*)(qrow + 32);
    }

    int frow[2]; u64 mf[2];
    #pragma unroll
    for (int fb = 0; fb < 2; fb++){ frow[fb] = f0w + 16*fb + c; mf[fb] = pmb[frow[fb]]; }

    f32x4 O[2][4];
    #pragma unroll
    for (int fb = 0; fb < 2; fb++)
      #pragma unroll
      for (int dt = 0; dt < 4; dt++) O[fb][dt] = (f32x4){0.f,0.f,0.f,0.f};
    float m_run[2] = {-1e30f, -1e30f};
    float l_run[2] = {0.f, 0.f};

    const int nT = 2*Fblk + 2;
    STAGE(0, 0)
    __syncthreads();
    int cur = 0;

    for (int it = 0; it < nT; ++it){
      const int t0 = it * 64;
      if (it + 1 < nT) STAGE(cur^1, (it+1)*64)

      if (t0 <= f0w + 31){
        const char* sKc = (const char*)sK[cur];
        const char* sVc = (const char*)sV[cur];

        f32x4 S[2][4];
        __builtin_amdgcn_s_setprio(1);
        #pragma unroll
        for (int ts = 0; ts < 4; ts++){
          int tl = ts*16 + c;
          const char* kr = sKc + tl*128;
          int sw = (tl & 7) << 4;
          bf16x8 kf0 = *(const bf16x8*)(kr + ((g*16) ^ sw));
          bf16x8 kf1 = *(const bf16x8*)(kr + ((64 + g*16) ^ sw));
          #pragma unroll
          for (int fb = 0; fb < 2; fb++){
            f32x4 a = (f32x4){0.f,0.f,0.f,0.f};
            a = __builtin_amdgcn_mfma_f32_16x16x32_bf16(kf0, qf[fb][0], a, 0, 0, 0);
            a = __builtin_amdgcn_mfma_f32_16x16x32_bf16(kf1, qf[fb][1], a, 0, 0, 0);
            S[fb][ts] = a;
          }
        }
        __builtin_amdgcn_s_setprio(0);

        u64 pmt[4][4];
        #pragma unroll
        for (int ts = 0; ts < 4; ts++){
          const u64* pp = pmb + t0 + 16*ts + 4*g;
          pmt[ts][0] = pp[0]; pmt[ts][1] = pp[1];
          pmt[ts][2] = pp[2]; pmt[ts][3] = pp[3];
        }

        #pragma unroll
        for (int fb = 0; fb < 2; fb++){
          int f = frow[fb];
          u64 mfr = mf[fb];
          #pragma unroll
          for (int ts = 0; ts < 4; ts++){
            #pragma unroll
            for (int r = 0; r < 4; r++){
              int t = t0 + 16*ts + 4*g + r;
              bool ok = (f == 0) ? (t == 0)
                       : (t > 0 && t <= f && ((pmt[ts][r] & mfr) != 0ull));
              if (!ok) S[fb][ts][r] = -1e30f;
            }
          }
          float mx = -1e30f;
          #pragma unroll
          for (int ts = 0; ts < 4; ts++)
            #pragma unroll
            for (int r = 0; r < 4; r++) mx = fmaxf(mx, S[fb][ts][r]);
          mx = fmaxf(mx, __shfl_xor(mx, 16));
          mx = fmaxf(mx, __shfl_xor(mx, 32));
          float mnew = fmaxf(m_run[fb], mx);
          float al = __expf(m_run[fb] - mnew);
          m_run[fb] = mnew;
          l_run[fb] *= al;
          #pragma unroll
          for (int dt = 0; dt < 4; dt++) O[fb][dt] *= al;

          int prow = 16*fb + c;
          int swz = (prow & 7) << 4;
          float lsum = 0.f;
          #pragma unroll
          for (int ts = 0; ts < 4; ts++){
            float p0 = __expf(S[fb][ts][0] - mnew);
            float p1 = __expf(S[fb][ts][1] - mnew);
            float p2 = __expf(S[fb][ts][2] - mnew);
            float p3 = __expf(S[fb][ts][3] - mnew);
            lsum += (p0 + p1) + (p2 + p3);
            uint2 dw = { pack2bf(p0, p1), pack2bf(p2, p3) };
            *(uint2*)(sPw + prow*128 + ((32*ts + 8*g) ^ swz)) = dw;
          }
          l_run[fb] += lsum;
        }

        bf16x8 pa[2][2];
        #pragma unroll
        for (int fb = 0; fb < 2; fb++){
          int prow = 16*fb + c;
          int swz = (prow & 7) << 4;
          const char* pr = sPw + prow*128;
          pa[fb][0] = *(const bf16x8*)(pr + ((16*g) ^ swz));
          pa[fb][1] = *(const bf16x8*)(pr + ((64 + 16*g) ^ swz));
        }
        __builtin_amdgcn_s_setprio(1);
        #pragma unroll
        for (int dt = 0; dt < 4; dt++){
          int vl = dt*16 + c;
          const char* vr = sVc + vl*128;
          int swv = (vl & 7) << 4;
          bf16x8 vf0 = *(const bf16x8*)(vr + ((g*16) ^ swv));
          bf16x8 vf1 = *(const bf16x8*)(vr + ((64 + g*16) ^ swv));
          #pragma unroll
          for (int fb = 0; fb < 2; fb++){
            O[fb][dt] = __builtin_amdgcn_mfma_f32_16x16x32_bf16(vf0, pa[fb][0], O[fb][dt], 0, 0, 0);
            O[fb][dt] = __builtin_amdgcn_mfma_f32_16x16x32_bf16(vf1, pa[fb][1], O[fb][dt], 0, 0, 0);
          }
        }
        __builtin_amdgcn_s_setprio(0);
      }

      __syncthreads();
      cur ^= 1;
    }

    #pragma unroll
    for (int fb = 0; fb < 2; fb++){
      float l = l_run[fb];
      l += __shfl_xor(l, 16);
      l += __shfl_xor(l, 32);
      float inv = 1.f / l;
      u16* ob = o + ((size_t)(b*Tt + frow[fb]))*Hh + n*HD;
      #pragma unroll
      for (int dt = 0; dt < 4; dt++){
        alignas(8) u16 tmp[4];
        #pragma unroll
        for (int r = 0; r < 4; r++) tmp[r] = f2bf(O[fb][dt][r] * inv);
        *(uint2*)(ob + dt*16 + 4*g) = *(const uint2*)tmp;
      }
    }
  }
  #undef STAGE
}

// ---------------- tail: skills + gather + sigmoid, one wave per row ----------------
__global__ __launch_bounds__(256) void k_tail(
    const u16* __restrict__ hidden, const int* __restrict__ prob_y2,
    const float* __restrict__ w_skill, const float* __restrict__ b_skill,
    const float* __restrict__ wpt, const float* __restrict__ b_prob,
    float* __restrict__ out)
{
  __shared__ float shid[4][104];
  int w = threadIdx.x >> 6, lane = threadIdx.x & 63;
  int row = blockIdx.x*4 + w;
  if (lane < 50){
    u32 hp = *(const u32*)(hidden + (size_t)row*128 + 2*lane);
    shid[w][2*lane]   = bf2f(hp & 0xffffu);
    shid[w][2*lane+1] = bf2f(hp >> 16);
  }
  __syncthreads();
  float s = 0.f;
  if (lane < 50){
    s = b_skill[lane];
    #pragma unroll 4
    for (int i = 0; i < 100; i++) s += shid[w][i] * w_skill[i*NSK + lane];
  }
  int np = (prob_y2[row] - 4) >> 1;
  float z = (lane < 50) ? s * wpt[(size_t)np*64 + lane] : 0.f;
  #pragma unroll
  for (int off = 1; off < 64; off <<= 1) z += __shfl_xor(z, off);
  if (lane == 0) out[row] = 1.f/(1.f + expf(-(z + b_prob[np])));
}

extern "C" void kernel_launch(void* const* d_in, const int* in_sizes, int n_in,
                              void* d_out, int out_size, void* d_ws, size_t ws_size,
                              hipStream_t stream)
{
  const int*   prob_x   = (const int*)d_in[0];
  const int*   prob_y2  = (const int*)d_in[1];
  const float* emb      = (const float*)d_in[2];
  const float* wq       = (const float*)d_in[3];
  const float* wk       = (const float*)d_in[4];
  const float* wv       = (const float*)d_in[5];
  const float* wo       = (const float*)d_in[6];
  const float* ln_g     = (const float*)d_in[7];
  const float* ln_b     = (const float*)d_in[8];
  const float* w_hid    = (const float*)d_in[9];
  const float* b_hid    = (const float*)d_in[10];
  const float* w_skill  = (const float*)d_in[11];
  const float* b_skill  = (const float*)d_in[12];
  const float* w_prob   = (const float*)d_in[13];
  const float* b_prob   = (const float*)d_in[14];
  const float* q_matrix = (const float*)d_in[15];
  float* out = (float*)d_out;

  char* ws = (char*)d_ws;
  const size_t M16 = (size_t)BT*Hh*2;   // 16 MiB
  u16*   xb     = (u16*)(ws);
  u16*   qb     = (u16*)(ws + M16);
  u16*   kb     = (u16*)(ws + 2*M16);
  u16*   vtb    = (u16*)(ws + 3*M16);
  u16*   att    = (u16*)(ws + 4*M16);
  u16*   y      = qb;      // dead after flash
  u16*   hidden = kb;      // dead after flash
  char*  aux    = ws + 5*M16;
  u16*   wqkvT  = (u16*)(aux);                            // 6 MiB
  u16*   woT    = wqkvT + (size_t)3*1024*1024;            // 2 MiB
  u16*   whT    = woT + (size_t)1024*1024;                // 256 KiB
  float* wpt    = (float*)(whT + (size_t)128*1024);       // 256 KiB
  u64*   pmask  = (u64*)(wpt + (size_t)NIT*64);           // 64 KiB
  float2* stats = (float2*)((char*)pmask + (size_t)BT*8); // 256 KiB used
  float2* uvp   = (float2*)((char*)stats + (size_t)BT*8*sizeof(float2)); // 32 KiB

  k_wT_all<<<dim3(32,32,7), 256, 0, stream>>>(wq, wk, wv, wo, w_hid, ln_g, ln_b,
                                              prob_x, q_matrix, w_prob,
                                              wqkvT, woT, whT, uvp, pmask, wpt);
  k_build_x2<<<BT, 256, 0, stream>>>(prob_x, emb, xb);

  k_gemm_qkv3<<<768, 512, 147456, stream>>>(xb, wqkvT, qb, kb, vtb);

  k_flash<<<dim3(Bb*NHd, 2), 256, 0, stream>>>(qb, kb, vtb, pmask, att);

  k_gemm_wo3<<<256, 512, 147456, stream>>>(att, woT, y, xb, stats);

  k_gemm_hidden<<<256, 256, 0, stream>>>(y, whT, stats, uvp, b_hid, hidden);

  k_tail<<<BT/4, 256, 0, stream>>>(hidden, prob_y2, w_skill, b_skill, wpt, b_prob, out);
}

// Round 13
// 168.343 us; speedup vs baseline: 1.1025x; 1.0481x over previous
//
#include <hip/hip_runtime.h>
#include <hip/hip_bf16.h>

#define Bb 16
#define Tt 512
#define Hh 1024
#define NHd 16
#define HD 64
#define BT (Bb*Tt)
#define NSK 50
#define NIT 1000

typedef __attribute__((ext_vector_type(8))) short bf16x8;
typedef __attribute__((ext_vector_type(4))) float f32x4;
typedef unsigned short u16;
typedef unsigned int u32;
typedef unsigned long long u64;

__device__ inline u16 f2bf(float x){
  union { float f; u32 u; } v; v.f = x;
  u32 r = v.u + 0x7fffu + ((v.u >> 16) & 1u);
  return (u16)(r >> 16);
}
__device__ inline float bf2f(u32 u){
  union { u32 uu; float f; } v; v.uu = u << 16; return v.f;
}
__device__ inline u32 pack2bf(float lo, float hi){
  return (u32)f2bf(lo) | ((u32)f2bf(hi) << 16);
}
__device__ inline void gload_lds16(const void* g, void* l){
  __builtin_amdgcn_global_load_lds(
    (const __attribute__((address_space(1))) u32*)g,
    (__attribute__((address_space(3))) u32*)l, 16, 0, 0);
}

// ---------------- weight transposes + pmask + wpt + uv partials, one launch ----------------
__global__ __launch_bounds__(256) void k_wT_all(
    const float* __restrict__ wq, const float* __restrict__ wk,
    const float* __restrict__ wv, const float* __restrict__ wo,
    const float* __restrict__ wh, const float* __restrict__ gamma,
    const float* __restrict__ beta,
    const int* __restrict__ prob_x, const float* __restrict__ qm,
    const float* __restrict__ wp,
    u16* __restrict__ wqkvT, u16* __restrict__ woT, u16* __restrict__ whT,
    float2* __restrict__ uvp, u64* __restrict__ pmask, float* __restrict__ wpt){
  int z = blockIdx.z;
  int tid = threadIdx.x;
  if (z == 5){
    if (blockIdx.y) return;
    int i = blockIdx.x*256 + tid;
    int pid = (prob_x[i] - 4) >> 1;
    u64 m = 0ull;
    #pragma unroll
    for (int s = 0; s < NSK; s++)
      if (qm[s*NIT + pid] != 0.f) m |= (1ull << s);
    pmask[i] = m;
    return;
  }
  if (z == 6){
    int blk = blockIdx.y*32 + blockIdx.x;
    if (blk >= 250) return;
    int p = blk*4 + (tid >> 6), lane = tid & 63;
    if (lane < NSK) wpt[(size_t)p*64 + lane] = wp[(size_t)lane*NIT + p];
    return;
  }
  const float* src; u16* dst; int C = 1024; float scale = 1.f; bool useg = false;
  if      (z == 0){ src = wq; dst = wqkvT;                       scale = 0.125f; }
  else if (z == 1){ src = wk; dst = wqkvT + (size_t)1024*1024; }
  else if (z == 2){ src = wv; dst = wqkvT + (size_t)2*1024*1024; }
  else if (z == 3){ src = wo; dst = woT; }
  else            { src = wh; dst = whT; C = 100; useg = true; if (blockIdx.x >= 4) return; }

  __shared__ float tile[32][33];
  int tx = tid & 31, ty = tid >> 5;
  int c0 = blockIdx.x*32, r0 = blockIdx.y*32;
  #pragma unroll
  for (int i = 0; i < 32; i += 8){
    int r = r0 + ty + i, cc = c0 + tx;
    tile[ty+i][tx] = (cc < C) ? src[(size_t)r*C + cc] : 0.f;
  }
  __syncthreads();
  float gmul = useg ? gamma[r0 + tx] : scale;
  #pragma unroll
  for (int i = 0; i < 32; i += 8){
    int cc = c0 + ty + i, rr = r0 + tx;
    dst[(size_t)cc*1024 + rr] = f2bf(tile[tx][ty+i] * gmul);
  }
  if (useg && tid < 32){
    int j = tid;
    float us = 0.f, vs = 0.f;
    #pragma unroll
    for (int k = 0; k < 32; k++){
      float wv2 = tile[k][j];
      us += gamma[r0 + k] * wv2;
      vs += beta[r0 + k] * wv2;
    }
    uvp[(size_t)blockIdx.y*128 + c0 + j] = make_float2(us, vs);
  }
}

// ---------------- x = emb[prob_x] + pe (inline) : bf16 ----------------
__global__ __launch_bounds__(256) void k_build_x2(
    const int* __restrict__ prob_x, const float* __restrict__ emb,
    u16* __restrict__ xb){
  int bt = blockIdx.x, tid = threadIdx.x;
  int t = bt & (Tt-1);
  int ix = prob_x[bt];
  int h = tid*4;
  float4 e = *(const float4*)(emb + (size_t)ix*Hh + h);
  const float LOG_INC = 0.0180241495f;   // ln(10000)/511
  int j0 = h >> 1;
  float a0 = (float)t * __expf(-(float)j0 * LOG_INC);
  float a1 = (float)t * __expf(-(float)(j0+1) * LOG_INC);
  alignas(8) u16 tmp[4] = { f2bf(e.x + __sinf(a0)), f2bf(e.y + __cosf(a0)),
                            f2bf(e.z + __sinf(a1)), f2bf(e.w + __cosf(a1)) };
  *(uint2*)(xb + (size_t)bt*Hh + h) = *(const uint2*)tmp;
}

// =========== 128(M) x 256(N) GEMM core: triple-buffered, 1 barrier/K-tile ===========
#define MFMA_(d, va, vb) d = __builtin_amdgcn_mfma_f32_16x16x32_bf16(va, vb, d, 0, 0, 0)

__device__ __forceinline__ void gemm128x256_core(
    const u16* __restrict__ A, const u16* __restrict__ Bt,
    int row0, int col0, char* lds, f32x4 (&acc)[4][4])
{
  const int tid = threadIdx.x, w = tid >> 6, lane = tid & 63;
  const int c = lane & 15, g = lane >> 4;
  const int wm = w >> 2, wn = w & 3;
  const int srl = lane >> 3, scb = lane & 7;
  const int kbsw = scb ^ srl;

  #define STAGE6(buf, k0)                                                        \
    do {                                                                         \
      char* _da = lds + (buf)*49152 + w*2048;                                    \
      char* _db = lds + (buf)*49152 + 16384 + w*4096;                            \
      _Pragma("unroll")                                                          \
      for (int i = 0; i < 2; i++)                                                \
        gload_lds16(A + (size_t)(row0 + 16*w + 8*i + srl)*1024 + (k0) + kbsw*8,  \
                    _da + i*1024);                                               \
      _Pragma("unroll")                                                          \
      for (int i = 0; i < 4; i++)                                                \
        gload_lds16(Bt + (size_t)(col0 + 32*w + 8*i + srl)*1024 + (k0) + kbsw*8, \
                    _db + i*1024);                                               \
    } while (0)

  STAGE6(0, 0);
  STAGE6(1, 64);
  asm volatile("s_waitcnt vmcnt(6)" ::: "memory");
  __builtin_amdgcn_s_barrier();

  #pragma unroll
  for (int kt = 0; kt < 16; ++kt){
    const int buf = kt % 3;
    if (kt + 2 < 16) STAGE6((kt + 2) % 3, (kt + 2)*64);

    bf16x8 af[2][4], bf[2][4];
    #pragma unroll
    for (int kh = 0; kh < 2; kh++){
      #pragma unroll
      for (int mi = 0; mi < 4; mi++){
        int r = 64*wm + 16*mi + c;
        af[kh][mi] = *(const bf16x8*)(lds + buf*49152 + r*128 + (((kh*4 + g) ^ (c & 7))*16));
      }
      #pragma unroll
      for (int ni = 0; ni < 4; ni++){
        int r = 64*wn + 16*ni + c;
        bf[kh][ni] = *(const bf16x8*)(lds + buf*49152 + 16384 + r*128 + (((kh*4 + g) ^ (c & 7))*16));
      }
    }
    __builtin_amdgcn_s_setprio(1);
    #pragma unroll
    for (int kh = 0; kh < 2; kh++)
      #pragma unroll
      for (int mi = 0; mi < 4; mi++)
        #pragma unroll
        for (int ni = 0; ni < 4; ni++) MFMA_(acc[mi][ni], af[kh][mi], bf[kh][ni]);
    __builtin_amdgcn_s_setprio(0);

    if (kt < 15){
      if (kt < 14) asm volatile("s_waitcnt vmcnt(6)" ::: "memory");
      else         asm volatile("s_waitcnt vmcnt(0)" ::: "memory");
      __builtin_amdgcn_s_barrier();
    }
  }
  #undef STAGE6
}

// =========== fused QKV GEMM: 768 blocks; XCD owns 8 row-panels, bx inner ===========
__global__ __launch_bounds__(512) void k_gemm_qkv3(
    const u16* __restrict__ A, const u16* __restrict__ Bt,
    u16* __restrict__ qb, u16* __restrict__ kb, u16* __restrict__ vtb)
{
  extern __shared__ char lds[];
  int lin = blockIdx.x;
  int xcd = lin & 7, j = lin >> 3;
  int by = xcd*8 + (j & 7);
  int bx = j >> 3;
  const int row0 = by*128, col0 = bx*256;

  f32x4 acc[4][4];
  #pragma unroll
  for (int mi = 0; mi < 4; mi++)
    #pragma unroll
    for (int ni = 0; ni < 4; ni++) acc[mi][ni] = (f32x4){0.f,0.f,0.f,0.f};

  gemm128x256_core(A, Bt, row0, col0, lds, acc);

  const int tid = threadIdx.x, w = tid >> 6, lane = tid & 63;
  const int c = lane & 15, g = lane >> 4;
  const int wm = w >> 2, wn = w & 3;
  int seg = col0 >> 10;
  int colL0 = col0 & 1023;
  if (seg < 2){
    u16* C = seg ? kb : qb;
    #pragma unroll
    for (int mi = 0; mi < 4; mi++){
      int m0 = row0 + 64*wm + 16*mi + 4*g;
      int bb = m0 >> 9, t0 = m0 & (Tt-1);
      #pragma unroll
      for (int ni = 0; ni < 4; ni++){
        int col = colL0 + 64*wn + 16*ni + c;
        int hd_ = col >> 6, d_ = col & 63;
        u16* base = C + (((size_t)bb*NHd + hd_)*Tt + t0)*HD + d_;
        #pragma unroll
        for (int r = 0; r < 4; r++) base[(size_t)r*HD] = f2bf(acc[mi][ni][r]);
      }
    }
  } else {
    #pragma unroll
    for (int mi = 0; mi < 4; mi++){
      int m0 = row0 + 64*wm + 16*mi + 4*g;
      int bb = m0 >> 9, t0 = m0 & (Tt-1);
      #pragma unroll
      for (int ni = 0; ni < 4; ni++){
        int col = colL0 + 64*wn + 16*ni + c;
        int hd_ = col >> 6, d_ = col & 63;
        alignas(8) u16 tmp[4];
        #pragma unroll
        for (int r = 0; r < 4; r++) tmp[r] = f2bf(acc[mi][ni][r]);
        *(uint2*)(vtb + (((size_t)bb*NHd + hd_)*HD + d_)*Tt + t0) = *(const uint2*)tmp;
      }
    }
  }
}

// =========== WO GEMM: 256 blocks; residual + LN stats ===========
__global__ __launch_bounds__(512) void k_gemm_wo3(
    const u16* __restrict__ A, const u16* __restrict__ Bt,
    u16* __restrict__ C, const u16* __restrict__ res, float2* __restrict__ stats)
{
  extern __shared__ char lds[];
  int lin = blockIdx.x;
  int xcd = lin & 7, j = lin >> 3;
  int by = xcd*8 + (j & 7);
  int bx = j >> 3;
  const int row0 = by*128, col0 = bx*256;

  f32x4 acc[4][4];
  #pragma unroll
  for (int mi = 0; mi < 4; mi++)
    #pragma unroll
    for (int ni = 0; ni < 4; ni++) acc[mi][ni] = (f32x4){0.f,0.f,0.f,0.f};

  gemm128x256_core(A, Bt, row0, col0, lds, acc);

  const int tid = threadIdx.x, w = tid >> 6, lane = tid & 63;
  const int c = lane & 15, g = lane >> 4;
  const int wm = w >> 2, wn = w & 3;

  float s1[4][4], s2[4][4];
  #pragma unroll
  for (int mi = 0; mi < 4; mi++)
    #pragma unroll
    for (int r = 0; r < 4; r++){ s1[mi][r] = 0.f; s2[mi][r] = 0.f; }

  #pragma unroll
  for (int mi = 0; mi < 4; mi++){
    int m0 = row0 + 64*wm + 16*mi + 4*g;
    #pragma unroll
    for (int ni = 0; ni < 4; ni++){
      int col = col0 + 64*wn + 16*ni + c;
      #pragma unroll
      for (int r = 0; r < 4; r++){
        size_t idx = (size_t)(m0 + r)*Hh + col;
        float yv = acc[mi][ni][r] + bf2f((u32)res[idx]);
        C[idx] = f2bf(yv);
        s1[mi][r] += yv; s2[mi][r] += yv*yv;
      }
    }
  }
  #pragma unroll
  for (int mi = 0; mi < 4; mi++)
    #pragma unroll
    for (int r = 0; r < 4; r++){
      #pragma unroll
      for (int off = 1; off < 16; off <<= 1){
        s1[mi][r] += __shfl_xor(s1[mi][r], off);
        s2[mi][r] += __shfl_xor(s2[mi][r], off);
      }
    }
  __syncthreads();
  float (*sStat)[4][2] = (float(*)[4][2])lds;
  if (c == 0){
    #pragma unroll
    for (int mi = 0; mi < 4; mi++)
      #pragma unroll
      for (int r = 0; r < 4; r++){
        int ml = 64*wm + 16*mi + 4*g + r;
        sStat[ml][wn][0] = s1[mi][r];
        sStat[ml][wn][1] = s2[mi][r];
      }
  }
  __syncthreads();
  if (tid < 128){
    float a = sStat[tid][0][0] + sStat[tid][1][0] + sStat[tid][2][0] + sStat[tid][3][0];
    float b = sStat[tid][0][1] + sStat[tid][1][1] + sStat[tid][2][1] + sStat[tid][3][1];
    stats[(size_t)(row0 + tid)*4 + bx] = make_float2(a, b);
  }
}

// =========== hidden GEMM with fused LayerNorm: BM=32, BN=128, 256 blocks ===========
__global__ __launch_bounds__(256) void k_gemm_hidden(
    const u16* __restrict__ A, const u16* __restrict__ Bt,
    const float2* __restrict__ stats, const float2* __restrict__ uvp,
    const float* __restrict__ b_hid, u16* __restrict__ C)
{
  __shared__ u16 sA[32*64];
  __shared__ u16 sB[128*64];
  __shared__ float sMu[32][2];
  __shared__ float2 sUV[128];
  const int tid = threadIdx.x, w = tid >> 6, lane = tid & 63;
  const int c = lane & 15, g = lane >> 4;
  const int row0 = blockIdx.x*32;
  const int srl = lane >> 3, scb = lane & 7;

  if (tid < 32){
    float m = 0.f, q = 0.f;
    #pragma unroll
    for (int cb = 0; cb < 4; cb++){
      float2 s = stats[(size_t)(row0 + tid)*4 + cb];
      m += s.x; q += s.y;
    }
    float mu = m * (1.f/Hh);
    float var = q * (1.f/Hh) - mu*mu;
    sMu[tid][0] = mu;
    sMu[tid][1] = rsqrtf(var + 1e-3f);
  }
  if (tid < 128){
    float us = 0.f, vs = 0.f;
    #pragma unroll 8
    for (int cb = 0; cb < 32; cb++){
      float2 p = uvp[(size_t)cb*128 + tid];
      us += p.x; vs += p.y;
    }
    float2 r = make_float2(0.f, 0.f);
    if (tid < 100){ r.x = us; r.y = vs + b_hid[tid]; }
    sUV[tid] = r;
  }

  f32x4 acc[2][2];
  #pragma unroll
  for (int mi = 0; mi < 2; mi++)
    #pragma unroll
    for (int ni = 0; ni < 2; ni++) acc[mi][ni] = (f32x4){0.f,0.f,0.f,0.f};

  for (int k0 = 0; k0 < 1024; k0 += 64){
    __syncthreads();
    {
      int arow = 8*w + srl;
      int kblk = scb ^ (arow & 7);
      gload_lds16(A + (size_t)(row0 + arow)*1024 + k0 + kblk*8,
                  (char*)sA + w*1024);
      #pragma unroll
      for (int i = 0; i < 4; i++){
        int brow = 32*w + 8*i + srl;
        int kb2 = scb ^ (brow & 7);
        gload_lds16(Bt + (size_t)brow*1024 + k0 + kb2*8,
                    (char*)sB + w*4096 + i*1024);
      }
    }
    __syncthreads();

    #pragma unroll
    for (int kh = 0; kh < 2; kh++){
      bf16x8 af[2], bf[2];
      #pragma unroll
      for (int mi = 0; mi < 2; mi++){
        int r = 16*mi + c;
        af[mi] = *(const bf16x8*)((char*)sA + r*128 + (((4*kh + g) ^ (r & 7))*16));
      }
      #pragma unroll
      for (int ni = 0; ni < 2; ni++){
        int r = 32*w + 16*ni + c;
        bf[ni] = *(const bf16x8*)((char*)sB + r*128 + (((4*kh + g) ^ (r & 7))*16));
      }
      #pragma unroll
      for (int mi = 0; mi < 2; mi++)
        #pragma unroll
        for (int ni = 0; ni < 2; ni++)
          acc[mi][ni] = __builtin_amdgcn_mfma_f32_16x16x32_bf16(af[mi], bf[ni], acc[mi][ni], 0, 0, 0);
    }
  }

  #pragma unroll
  for (int mi = 0; mi < 2; mi++){
    #pragma unroll
    for (int ni = 0; ni < 2; ni++){
      int col = 32*w + 16*ni + c;
      float2 uvv = sUV[col];
      #pragma unroll
      for (int r = 0; r < 4; r++){
        int ml = 16*mi + 4*g + r;
        float mu = sMu[ml][0], inv = sMu[ml][1];
        float h = fmaxf(inv*(acc[mi][ni][r] - mu*uvv.x) + uvv.y, 0.f);
        C[(size_t)(row0 + ml)*128 + col] = f2bf(h);
      }
    }
  }
}

// =========== MFMA flash attention, swapped-operand structure ===========
__global__ __launch_bounds__(256, 3) void k_flash(
    const u16* __restrict__ qb, const u16* __restrict__ kb,
    const u16* __restrict__ vtb, const u64* __restrict__ pmask,
    u16* __restrict__ o)
{
  __shared__ u16 sK[2][64*64];
  __shared__ u16 sV[2][64*64];
  __shared__ u16 sP[4][32*64];

  const int tid = threadIdx.x;
  const int w = tid >> 6, lane = tid & 63;
  const int c = lane & 15, g = lane >> 4;
  const int bn = blockIdx.x;
  const int Fblk = 3 - blockIdx.y;
  const int b = bn >> 4, n = bn & 15;
  const int f0w = Fblk*128 + w*32;

  bf16x8 qf[2][2];
  #pragma unroll
  for (int fb = 0; fb < 2; fb++){
    const u16* qrow = qb + ((size_t)bn*Tt + f0w + 16*fb + c)*HD + 8*g;
    qf[fb][0] = *(const bf16x8*)(qrow);
    qf[fb][1] = *(const bf16x8*)(qrow + 32);
  }

  const u64* pmb = pmask + b*Tt;
  int frow[2]; u64 mf[2];
  #pragma unroll
  for (int fb = 0; fb < 2; fb++){ frow[fb] = f0w + 16*fb + c; mf[fb] = pmb[frow[fb]]; }

  f32x4 O[2][4];
  #pragma unroll
  for (int fb = 0; fb < 2; fb++)
    #pragma unroll
    for (int dt = 0; dt < 4; dt++) O[fb][dt] = (f32x4){0.f,0.f,0.f,0.f};
  float m_run[2] = {-1e30f, -1e30f};
  float l_run[2] = {0.f, 0.f};

  const char* kbase = (const char*)(kb + (size_t)bn*Tt*HD);
  const char* vbase = (const char*)(vtb + (size_t)bn*HD*Tt);
  char* sPw = (char*)(sP[w]);

  const int srow0 = 16*w + (lane >> 3);
  const int scb = lane & 7;

  #define STAGE(buf, T0)                                                          \
    {                                                                             \
      _Pragma("unroll")                                                           \
      for (int i = 0; i < 2; i++){                                                \
        int row = srow0 + 8*i;                                                    \
        int cb = scb ^ (row & 7);                                                 \
        gload_lds16(kbase + (size_t)((T0) + row)*128 + cb*16,                     \
                    (char*)sK[buf] + w*2048 + i*1024);                            \
        gload_lds16(vbase + (size_t)row*1024 + (T0)*2 + cb*16,                    \
                    (char*)sV[buf] + w*2048 + i*1024);                            \
      }                                                                           \
    }

  const int nT = 2*Fblk + 2;
  STAGE(0, 0)
  __syncthreads();
  int cur = 0;

  for (int it = 0; it < nT; ++it){
    const int t0 = it * 64;
    if (it + 1 < nT) STAGE(cur^1, (it+1)*64)

    if (t0 <= f0w + 31){
      const char* sKc = (const char*)sK[cur];
      const char* sVc = (const char*)sV[cur];

      f32x4 S[2][4];
      __builtin_amdgcn_s_setprio(1);
      #pragma unroll
      for (int ts = 0; ts < 4; ts++){
        int tl = ts*16 + c;
        const char* kr = sKc + tl*128;
        int sw = (tl & 7) << 4;
        bf16x8 kf0 = *(const bf16x8*)(kr + ((g*16) ^ sw));
        bf16x8 kf1 = *(const bf16x8*)(kr + ((64 + g*16) ^ sw));
        #pragma unroll
        for (int fb = 0; fb < 2; fb++){
          f32x4 a = (f32x4){0.f,0.f,0.f,0.f};
          a = __builtin_amdgcn_mfma_f32_16x16x32_bf16(kf0, qf[fb][0], a, 0, 0, 0);
          a = __builtin_amdgcn_mfma_f32_16x16x32_bf16(kf1, qf[fb][1], a, 0, 0, 0);
          S[fb][ts] = a;
        }
      }
      __builtin_amdgcn_s_setprio(0);

      u64 pmt[4][4];
      #pragma unroll
      for (int ts = 0; ts < 4; ts++){
        const u64* pp = pmb + t0 + 16*ts + 4*g;
        pmt[ts][0] = pp[0]; pmt[ts][1] = pp[1];
        pmt[ts][2] = pp[2]; pmt[ts][3] = pp[3];
      }

      #pragma unroll
      for (int fb = 0; fb < 2; fb++){
        int f = frow[fb];
        u64 mfr = mf[fb];
        #pragma unroll
        for (int ts = 0; ts < 4; ts++){
          #pragma unroll
          for (int r = 0; r < 4; r++){
            int t = t0 + 16*ts + 4*g + r;
            bool ok = (f == 0) ? (t == 0)
                     : (t > 0 && t <= f && ((pmt[ts][r] & mfr) != 0ull));
            if (!ok) S[fb][ts][r] = -1e30f;
          }
        }
        float mx = -1e30f;
        #pragma unroll
        for (int ts = 0; ts < 4; ts++)
          #pragma unroll
          for (int r = 0; r < 4; r++) mx = fmaxf(mx, S[fb][ts][r]);
        mx = fmaxf(mx, __shfl_xor(mx, 16));
        mx = fmaxf(mx, __shfl_xor(mx, 32));
        float mnew = fmaxf(m_run[fb], mx);
        float al = __expf(m_run[fb] - mnew);
        m_run[fb] = mnew;
        l_run[fb] *= al;
        #pragma unroll
        for (int dt = 0; dt < 4; dt++) O[fb][dt] *= al;

        int prow = 16*fb + c;
        int swz = (prow & 7) << 4;
        float lsum = 0.f;
        #pragma unroll
        for (int ts = 0; ts < 4; ts++){
          float p0 = __expf(S[fb][ts][0] - mnew);
          float p1 = __expf(S[fb][ts][1] - mnew);
          float p2 = __expf(S[fb][ts][2] - mnew);
          float p3 = __expf(S[fb][ts][3] - mnew);
          lsum += (p0 + p1) + (p2 + p3);
          uint2 dw = { pack2bf(p0, p1), pack2bf(p2, p3) };
          *(uint2*)(sPw + prow*128 + ((32*ts + 8*g) ^ swz)) = dw;
        }
        l_run[fb] += lsum;
      }

      bf16x8 pa[2][2];
      #pragma unroll
      for (int fb = 0; fb < 2; fb++){
        int prow = 16*fb + c;
        int swz = (prow & 7) << 4;
        const char* pr = sPw + prow*128;
        pa[fb][0] = *(const bf16x8*)(pr + ((16*g) ^ swz));
        pa[fb][1] = *(const bf16x8*)(pr + ((64 + 16*g) ^ swz));
      }
      __builtin_amdgcn_s_setprio(1);
      #pragma unroll
      for (int dt = 0; dt < 4; dt++){
        int vl = dt*16 + c;
        const char* vr = sVc + vl*128;
        int swv = (vl & 7) << 4;
        bf16x8 vf0 = *(const bf16x8*)(vr + ((g*16) ^ swv));
        bf16x8 vf1 = *(const bf16x8*)(vr + ((64 + g*16) ^ swv));
        #pragma unroll
        for (int fb = 0; fb < 2; fb++){
          O[fb][dt] = __builtin_amdgcn_mfma_f32_16x16x32_bf16(vf0, pa[fb][0], O[fb][dt], 0, 0, 0);
          O[fb][dt] = __builtin_amdgcn_mfma_f32_16x16x32_bf16(vf1, pa[fb][1], O[fb][dt], 0, 0, 0);
        }
      }
      __builtin_amdgcn_s_setprio(0);
    }

    __syncthreads();
    cur ^= 1;
  }
  #undef STAGE

  #pragma unroll
  for (int fb = 0; fb < 2; fb++){
    float l = l_run[fb];
    l += __shfl_xor(l, 16);
    l += __shfl_xor(l, 32);
    float inv = 1.f / l;
    u16* ob = o + ((size_t)(b*Tt + frow[fb]))*Hh + n*HD;
    #pragma unroll
    for (int dt = 0; dt < 4; dt++){
      alignas(8) u16 tmp[4];
      #pragma unroll
      for (int r = 0; r < 4; r++) tmp[r] = f2bf(O[fb][dt][r] * inv);
      *(uint2*)(ob + dt*16 + 4*g) = *(const uint2*)tmp;
    }
  }
}

// ---------------- tail: skills + gather + sigmoid, one wave per row ----------------
__global__ __launch_bounds__(256) void k_tail(
    const u16* __restrict__ hidden, const int* __restrict__ prob_y2,
    const float* __restrict__ w_skill, const float* __restrict__ b_skill,
    const float* __restrict__ wpt, const float* __restrict__ b_prob,
    float* __restrict__ out)
{
  __shared__ float shid[4][104];
  int w = threadIdx.x >> 6, lane = threadIdx.x & 63;
  int row = blockIdx.x*4 + w;
  if (lane < 50){
    u32 hp = *(const u32*)(hidden + (size_t)row*128 + 2*lane);
    shid[w][2*lane]   = bf2f(hp & 0xffffu);
    shid[w][2*lane+1] = bf2f(hp >> 16);
  }
  __syncthreads();
  float s = 0.f;
  if (lane < 50){
    s = b_skill[lane];
    #pragma unroll 4
    for (int i = 0; i < 100; i++) s += shid[w][i] * w_skill[i*NSK + lane];
  }
  int np = (prob_y2[row] - 4) >> 1;
  float z = (lane < 50) ? s * wpt[(size_t)np*64 + lane] : 0.f;
  #pragma unroll
  for (int off = 1; off < 64; off <<= 1) z += __shfl_xor(z, off);
  if (lane == 0) out[row] = 1.f/(1.f + expf(-(z + b_prob[np])));
}

extern "C" void kernel_launch(void* const* d_in, const int* in_sizes, int n_in,
                              void* d_out, int out_size, void* d_ws, size_t ws_size,
                              hipStream_t stream)
{
  const int*   prob_x   = (const int*)d_in[0];
  const int*   prob_y2  = (const int*)d_in[1];
  const float* emb      = (const float*)d_in[2];
  const float* wq       = (const float*)d_in[3];
  const float* wk       = (const float*)d_in[4];
  const float* wv       = (const float*)d_in[5];
  const float* wo       = (const float*)d_in[6];
  const float* ln_g     = (const float*)d_in[7];
  const float* ln_b     = (const float*)d_in[8];
  const float* w_hid    = (const float*)d_in[9];
  const float* b_hid    = (const float*)d_in[10];
  const float* w_skill  = (const float*)d_in[11];
  const float* b_skill  = (const float*)d_in[12];
  const float* w_prob   = (const float*)d_in[13];
  const float* b_prob   = (const float*)d_in[14];
  const float* q_matrix = (const float*)d_in[15];
  float* out = (float*)d_out;

  char* ws = (char*)d_ws;
  const size_t M16 = (size_t)BT*Hh*2;   // 16 MiB
  u16*   xb     = (u16*)(ws);
  u16*   qb     = (u16*)(ws + M16);
  u16*   kb     = (u16*)(ws + 2*M16);
  u16*   vtb    = (u16*)(ws + 3*M16);
  u16*   att    = (u16*)(ws + 4*M16);
  u16*   y      = qb;      // dead after flash
  u16*   hidden = kb;      // dead after flash
  char*  aux    = ws + 5*M16;
  u16*   wqkvT  = (u16*)(aux);                            // 6 MiB
  u16*   woT    = wqkvT + (size_t)3*1024*1024;            // 2 MiB
  u16*   whT    = woT + (size_t)1024*1024;                // 256 KiB
  float* wpt    = (float*)(whT + (size_t)128*1024);       // 256 KiB
  u64*   pmask  = (u64*)(wpt + (size_t)NIT*64);           // 64 KiB
  float2* stats = (float2*)((char*)pmask + (size_t)BT*8); // 256 KiB used
  float2* uvp   = (float2*)((char*)stats + (size_t)BT*8*sizeof(float2)); // 32 KiB

  k_wT_all<<<dim3(32,32,7), 256, 0, stream>>>(wq, wk, wv, wo, w_hid, ln_g, ln_b,
                                              prob_x, q_matrix, w_prob,
                                              wqkvT, woT, whT, uvp, pmask, wpt);
  k_build_x2<<<BT, 256, 0, stream>>>(prob_x, emb, xb);

  k_gemm_qkv3<<<768, 512, 147456, stream>>>(xb, wqkvT, qb, kb, vtb);

  k_flash<<<dim3(Bb*NHd, 4), 256, 0, stream>>>(qb, kb, vtb, pmask, att);

  k_gemm_wo3<<<256, 512, 147456, stream>>>(att, woT, y, xb, stats);

  k_gemm_hidden<<<256, 256, 0, stream>>>(y, whT, stats, uvp, b_hid, hidden);

  k_tail<<<BT/4, 256, 0, stream>>>(hidden, prob_y2, w_skill, b_skill, wpt, b_prob, out);
}